// Round 2
// baseline (7742.028 us; speedup 1.0000x reference)
//
#include <hip/hip_runtime.h>
#include <math.h>

// Problem constants
#define BB   32
#define NN   200
#define SS   192
#define FIN  8
#define HH   64
#define PP   48
#define FNN  4
#define KK   10
#define NBLK 3
#define EPSF 1e-5f
#define SH   (SS*HH)               // 12288
#define XSZ  ((size_t)BB*NN*SS*HH) // 78,643,200 elements
#define ROWS (BB*NN)               // 6400
#define SCH  48                    // s-chunk for spatial z
#define NCH  (SS/SCH)              // 4 chunks
#define CCH  (SCH*HH)              // 3072 cols per chunk

// bf16 <-> f32 helpers on raw ushort storage
__device__ __forceinline__ float bf2f(unsigned short u) {
    union { unsigned int i; float f; } v; v.i = ((unsigned int)u) << 16; return v.f;
}
__device__ __forceinline__ unsigned short f2bf(float f) {
    union { float f; unsigned int i; } v; v.f = f;
    unsigned int r = v.i + 0x7FFFu + ((v.i >> 16) & 1u);   // round-nearest-even
    return (unsigned short)(r >> 16);
}

__device__ __forceinline__ float wave_sum(float v) {
    #pragma unroll
    for (int off = 32; off > 0; off >>= 1) v += __shfl_xor(v, off, 64);
    return v;
}
__device__ __forceinline__ float wave_max(float v) {
    #pragma unroll
    for (int off = 32; off > 0; off >>= 1) v = fmaxf(v, __shfl_xor(v, off, 64));
    return v;
}

// ---------------------------------------------------------------------------
// Adjacency: la = relu(E E^T); top-K mask; softmax; blend with adj; diag=1;
// then symmetric D^-1/2 normalization. One wave per row.
// ---------------------------------------------------------------------------
__global__ void k_adj_row(const float* __restrict__ emb, const float* __restrict__ adj,
                          const float* __restrict__ alpha_p,
                          float* __restrict__ Araw, float* __restrict__ dvec) {
    int r = blockIdx.x;
    int lane = threadIdx.x;
    __shared__ float er[HH];
    __shared__ float la[NN];
    __shared__ float tmp[NN];
    __shared__ float keep[NN];
    er[lane] = emb[r*HH + lane];
    __syncthreads();
    for (int j = lane; j < NN; j += 64) {
        float d = 0.f;
        #pragma unroll 8
        for (int h = 0; h < HH; ++h) d += er[h] * emb[j*HH + h];
        float v = fmaxf(d, 0.f);
        la[j] = v; tmp[j] = v; keep[j] = 0.f;
    }
    __syncthreads();
    // top-K, jax.lax.top_k tie semantics (equal values -> lower index wins)
    for (int it = 0; it < KK; ++it) {
        float bv = -1.f; int bi = NN;
        for (int j = lane; j < NN; j += 64) {
            float v = tmp[j];
            if (v > bv) { bv = v; bi = j; }
        }
        #pragma unroll
        for (int off = 32; off > 0; off >>= 1) {
            float ov = __shfl_xor(bv, off, 64);
            int   oi = __shfl_xor(bi, off, 64);
            if (ov > bv || (ov == bv && oi < bi)) { bv = ov; bi = oi; }
        }
        if (lane == 0) { keep[bi] = 1.f; tmp[bi] = -1.f; }
        __syncthreads();
    }
    // masked softmax over all 200 columns (masked entries contribute exp(0-m))
    float mloc = 0.f;
    for (int j = lane; j < NN; j += 64) {
        float v = (keep[j] > 0.f) ? la[j] : 0.f;
        tmp[j] = v;
        mloc = fmaxf(mloc, v);
    }
    float m = wave_max(mloc);
    float sloc = 0.f;
    for (int j = lane; j < NN; j += 64) sloc += expf(tmp[j] - m);
    float ssum = wave_sum(sloc);
    float alpha = alpha_p[0];
    float rloc = 0.f;
    for (int j = lane; j < NN; j += 64) {
        float soft = expf(tmp[j] - m) / ssum;
        float comb = alpha * adj[r*NN + j] + (1.f - alpha) * soft;
        float a = (j == r) ? 1.f : comb;
        Araw[r*NN + j] = a;
        rloc += a;
    }
    float rs = wave_sum(rloc);
    if (lane == 0) dvec[r] = 1.f / sqrtf(fmaxf(rs, 1.f));
}

__global__ void k_adj_scale(const float* __restrict__ Araw, const float* __restrict__ dvec,
                            float* __restrict__ Amat) {
    int r = blockIdx.x, j = threadIdx.x;
    if (j < NN) Amat[r*NN + j] = Araw[r*NN + j] * dvec[r] * dvec[j];
}

// ---------------------------------------------------------------------------
// Stage0: InstanceNorm over S (per b,n,f) -> proj (8 -> 64) -> +emb. bf16 out.
// One wave per (b,n).
// ---------------------------------------------------------------------------
__global__ void k_stage0(const float* __restrict__ x, const float* __restrict__ inw,
                         const float* __restrict__ inb, const float* __restrict__ pW,
                         const float* __restrict__ pb, const float* __restrict__ emb,
                         unsigned short* __restrict__ X) {
    int bn = blockIdx.x;
    int lane = threadIdx.x;
    int n = bn % NN;
    __shared__ float xl[SS*FIN];
    const float* xp = x + (size_t)bn*SS*FIN;
    for (int i = lane; i < SS*FIN; i += 64) xl[i] = xp[i];
    __syncthreads();
    float sum8[FIN], sq8[FIN];
    #pragma unroll
    for (int f = 0; f < FIN; ++f) { sum8[f] = 0.f; sq8[f] = 0.f; }
    #pragma unroll
    for (int k = 0; k < 3; ++k) {
        int s = lane*3 + k;
        #pragma unroll
        for (int f = 0; f < FIN; ++f) {
            float v = xl[s*FIN + f];
            sum8[f] += v; sq8[f] += v*v;
        }
    }
    #pragma unroll
    for (int f = 0; f < FIN; ++f) { sum8[f] = wave_sum(sum8[f]); sq8[f] = wave_sum(sq8[f]); }
    float scal[FIN], bias[FIN];
    #pragma unroll
    for (int f = 0; f < FIN; ++f) {
        float mu  = sum8[f] * (1.f/SS);
        float var = sq8[f] * (1.f/SS) - mu*mu;
        float sc  = inw[f] / sqrtf(var + EPSF);
        scal[f] = sc;
        bias[f] = inb[f] - mu*sc;
    }
    float pwr[FIN];
    #pragma unroll
    for (int f = 0; f < FIN; ++f) pwr[f] = pW[f*HH + lane];
    float cst = pb[lane] + emb[n*HH + lane];
    unsigned short* op = X + (size_t)bn*SH;
    for (int s = 0; s < SS; ++s) {
        float acc = cst;
        #pragma unroll
        for (int f = 0; f < FIN; ++f) acc += (xl[s*FIN + f]*scal[f] + bias[f]) * pwr[f];
        op[s*HH + lane] = f2bf(acc);
    }
}

// ---------------------------------------------------------------------------
// Temporal (IN-PLACE): x[t,h] += gelu( sum_s W[t,s]*x[s,h] + tb[t] )
// Block per (b,n); full row tile staged in LDS before the barrier, so the
// in-place global write is race-free.
// ---------------------------------------------------------------------------
__global__ __launch_bounds__(256) void k_temporal(unsigned short* __restrict__ X,
        const float* __restrict__ tW, const float* __restrict__ tb) {
    __shared__ float xl[SH];   // 48 KB
    int bn = blockIdx.x, tid = threadIdx.x;
    unsigned short* xp = X + (size_t)bn*SH;
    const unsigned int* xp32 = (const unsigned int*)xp;
    for (int i = tid; i < SH/2; i += 256) {
        unsigned int u = xp32[i];
        xl[2*i]   = bf2f((unsigned short)(u & 0xffffu));
        xl[2*i+1] = bf2f((unsigned short)(u >> 16));
    }
    __syncthreads();
    int h = tid & 63, tg = tid >> 6;
    for (int batch = 0; batch < 6; ++batch) {
        int t0 = __builtin_amdgcn_readfirstlane(tg*48 + batch*8);
        float acc[8];
        #pragma unroll
        for (int j = 0; j < 8; ++j) acc[j] = tb[t0 + j];
        #pragma unroll 4
        for (int s = 0; s < SS; ++s) {
            float xv = xl[s*HH + h];
            #pragma unroll
            for (int j = 0; j < 8; ++j) acc[j] += tW[(t0 + j)*SS + s] * xv;
        }
        #pragma unroll
        for (int j = 0; j < 8; ++j) {
            float y = acc[j];
            float g = 0.5f * y * (1.f + erff(y * 0.70710678118f));
            xp[(t0 + j)*HH + h] = f2bf(xl[(t0 + j)*HH + h] + g);
        }
    }
}

// ---------------------------------------------------------------------------
// Spatial part 1 (per s-chunk): z[b,m,cc] = sum_n A[m,n] * x[b,n,s0*64+cc]
// Outer-product tiling: 40 m-rows per block (A via wave-uniform s_loads),
// 256 chunk-columns per block.
// ---------------------------------------------------------------------------
#define TMS 40
__global__ __launch_bounds__(256) void k_spatial1(const unsigned short* __restrict__ X,
        const float* __restrict__ Amat, unsigned short* __restrict__ Z, int s0) {
    int ct = blockIdx.x, mt = blockIdx.y, b = blockIdx.z;
    int tid = threadIdx.x;
    int m0 = mt * TMS;
    int cc = ct*256 + tid;                 // 0..3071 within chunk
    int col = s0*HH + cc;                  // global column
    const unsigned short* xp = X + (size_t)b*NN*SH + col;
    const float* ap = Amat + (size_t)m0*NN;
    float acc[TMS];
    #pragma unroll
    for (int i = 0; i < TMS; ++i) acc[i] = 0.f;
    #pragma unroll 2
    for (int n = 0; n < NN; ++n) {
        float v = bf2f(xp[(size_t)n*SH]);
        #pragma unroll
        for (int i = 0; i < TMS; ++i) acc[i] += ap[i*NN + n] * v;
    }
    unsigned short* zp = Z + ((size_t)b*NN + m0)*CCH + cc;
    #pragma unroll
    for (int i = 0; i < TMS; ++i) zp[(size_t)i*CCH] = f2bf(acc[i]);
}

// ---------------------------------------------------------------------------
// Spatial part 2 (per s-chunk, IN-PLACE on X):
//   x = LayerNorm_h( x + z @ gcn_W + gcn_b ) * ln_w + ln_b
// Block per (b,m). Lane = h. z chunk rows + gcn_W staged in LDS.
// ---------------------------------------------------------------------------
__global__ __launch_bounds__(256) void k_spatial2(unsigned short* __restrict__ X,
        const unsigned short* __restrict__ Z, const float* __restrict__ gW,
        const float* __restrict__ gb, const float* __restrict__ lnw,
        const float* __restrict__ lnb, int s0) {
    __shared__ float wl[HH*HH];     // 16 KB
    __shared__ float zl[SCH*HH];    // 12 KB
    int bm = blockIdx.x, tid = threadIdx.x;
    for (int i = tid; i < HH*HH; i += 256) wl[i] = gW[i];
    const unsigned short* zrow = Z + (size_t)bm*CCH;
    for (int i = tid; i < CCH; i += 256) zl[i] = bf2f(zrow[i]);
    __syncthreads();
    int h = tid & 63, wg = tid >> 6;
    float gbh = gb[h], lwh = lnw[h], lbh = lnb[h];
    size_t base = (size_t)bm*SH;
    for (int it = 0; it < 3; ++it) {
        int r0 = wg*12 + it*4;             // 4 rows per iteration
        float acc[4];
        #pragma unroll
        for (int j = 0; j < 4; ++j) acc[j] = 0.f;
        #pragma unroll 4
        for (int hp = 0; hp < HH; ++hp) {
            float w = wl[hp*HH + h];
            #pragma unroll
            for (int j = 0; j < 4; ++j) acc[j] += zl[(r0 + j)*HH + hp] * w;
        }
        #pragma unroll
        for (int j = 0; j < 4; ++j) {
            size_t gi = base + (size_t)(s0 + r0 + j)*HH + h;
            float v = bf2f(X[gi]) + acc[j] + gbh;
            float mu = wave_sum(v) * (1.f/64.f);
            float d = v - mu;
            float var = wave_sum(d*d) * (1.f/64.f);
            X[gi] = f2bf(d * (1.f / sqrtf(var + EPSF)) * lwh + lbh);
        }
    }
}

// ---------------------------------------------------------------------------
// Head: out[row,p] = concat(x_hist, x_futr)[row,:] @ head_W + head_b
// 32 rows x 48 p per block, 4-way split-K over 15360, atomicAdd combine.
// ---------------------------------------------------------------------------
__global__ __launch_bounds__(192) void k_head(const unsigned short* __restrict__ Xf,
        const float* __restrict__ xfut, const float* __restrict__ fW,
        const float* __restrict__ fb, const float* __restrict__ hW,
        const float* __restrict__ hb, float* __restrict__ out) {
    __shared__ float Wl[64*PP];   // 12 KB
    __shared__ float ft[32*64];   // 8 KB
    int ct = blockIdx.x, rt = blockIdx.y;
    int tid = threadIdx.x;
    int p = tid % PP, mq = tid / PP;       // mq in 0..3
    int r0 = rt*32, c0 = ct*3840;
    float acc[8];
    #pragma unroll
    for (int j = 0; j < 8; ++j) acc[j] = (ct == 0) ? hb[p] : 0.f;
    for (int cc0 = 0; cc0 < 3840; cc0 += 64) {
        int cg = c0 + cc0;
        for (int i = tid; i < 64*PP; i += 192) Wl[i] = hW[(size_t)cg*PP + i];
        for (int i = tid; i < 2048; i += 192) {
            int mi = i >> 6, ccc = i & 63;
            int row = r0 + mi, cglob = cg + ccc;
            float v;
            if (cglob < SH) {
                v = bf2f(Xf[(size_t)row*SH + cglob]);
            } else {
                int cp = cglob - SH, ppp = cp >> 6, hh = cp & 63;
                v = fb[hh];
                #pragma unroll
                for (int f = 0; f < FNN; ++f)
                    v += xfut[((size_t)row*PP + ppp)*FNN + f] * fW[f*HH + hh];
            }
            ft[i] = v;
        }
        __syncthreads();
        #pragma unroll 4
        for (int ccc = 0; ccc < 64; ++ccc) {
            float w = Wl[ccc*PP + p];
            #pragma unroll
            for (int j = 0; j < 8; ++j) acc[j] += ft[(mq*8 + j)*64 + ccc] * w;
        }
        __syncthreads();
    }
    #pragma unroll
    for (int j = 0; j < 8; ++j)
        atomicAdd(&out[(size_t)(r0 + mq*8 + j)*PP + p], acc[j]);
}

// ---------------------------------------------------------------------------
extern "C" void kernel_launch(void* const* d_in, const int* in_sizes, int n_in,
                              void* d_out, int out_size, void* d_ws, size_t ws_size,
                              hipStream_t stream) {
    const float* x     = (const float*)d_in[0];
    const float* xfut  = (const float*)d_in[1];
    const float* adj   = (const float*)d_in[2];
    const float* emb   = (const float*)d_in[3];
    const float* alpha = (const float*)d_in[4];
    const float* inw   = (const float*)d_in[5];
    const float* inb   = (const float*)d_in[6];
    const float* pW    = (const float*)d_in[7];
    const float* pb    = (const float*)d_in[8];
    const float* tW    = (const float*)d_in[9];
    const float* tb    = (const float*)d_in[10];
    const float* gW    = (const float*)d_in[11];
    const float* gb    = (const float*)d_in[12];
    const float* lnw   = (const float*)d_in[13];
    const float* lnb   = (const float*)d_in[14];
    const float* fW    = (const float*)d_in[15];
    const float* fb    = (const float*)d_in[16];
    const float* hW    = (const float*)d_in[17];
    const float* hb    = (const float*)d_in[18];
    float* out = (float*)d_out;

    // Workspace layout (~197 MB total):
    //   bufX : bf16 X tensor, XSZ elems            = 157.3 MB
    //   bufZ : bf16 z chunk, BB*NN*CCH elems       =  39.3 MB
    //   Amat/Araw/dvec : adjacency fp32            =   0.32 MB
    unsigned short* bufX = (unsigned short*)d_ws;
    unsigned short* bufZ = bufX + XSZ;
    float* Amat = (float*)(bufZ + (size_t)BB*NN*CCH);
    float* Araw = Amat + NN*NN;
    float* dvec = Araw + NN*NN;

    hipMemsetAsync(d_out, 0, (size_t)ROWS*PP*sizeof(float), stream);
    k_adj_row<<<NN, 64, 0, stream>>>(emb, adj, alpha, Araw, dvec);
    k_adj_scale<<<NN, 256, 0, stream>>>(Araw, dvec, Amat);
    k_stage0<<<ROWS, 64, 0, stream>>>(x, inw, inb, pW, pb, emb, bufX);

    for (int i = 0; i < NBLK; ++i) {
        k_temporal<<<ROWS, 256, 0, stream>>>(bufX, tW + i*SS*SS, tb + i*SS);
        for (int ch = 0; ch < NCH; ++ch) {
            k_spatial1<<<dim3(CCH/256, NN/TMS, BB), 256, 0, stream>>>(bufX, Amat, bufZ, ch*SCH);
            k_spatial2<<<ROWS, 256, 0, stream>>>(bufX, bufZ, gW + i*HH*HH, gb + i*HH,
                                                 lnw + i*HH, lnb + i*HH, ch*SCH);
        }
    }
    k_head<<<dim3(4, 200), 192, 0, stream>>>(bufX, xfut, fW, fb, hW, hb, out);
}

// Round 3
// 2168.554 us; speedup vs baseline: 3.5701x; 3.5701x over previous
//
#include <hip/hip_runtime.h>
#include <math.h>

// Problem constants
#define BB   32
#define NN   200
#define SS   192
#define FIN  8
#define HH   64
#define PP   48
#define FNN  4
#define KK   10
#define NBLK 3
#define EPSF 1e-5f
#define SH   (SS*HH)               // 12288
#define XSZ  ((size_t)BB*NN*SS*HH) // 78,643,200 elements
#define ROWS (BB*NN)               // 6400
#define SCH  48                    // s-chunk for spatial z
#define NCH  (SS/SCH)              // 4 chunks
#define CCH  (SCH*HH)              // 3072 cols per chunk
#define NPAD 208                   // node dim padded (N of spatial1)
#define KPAD 224                   // node contraction padded (K of spatial1)

typedef __attribute__((ext_vector_type(8))) short bf16x8;
typedef __attribute__((ext_vector_type(4))) float f32x4;

// bf16 <-> f32 helpers on raw ushort storage
__device__ __forceinline__ float bf2f(unsigned short u) {
    union { unsigned int i; float f; } v; v.i = ((unsigned int)u) << 16; return v.f;
}
__device__ __forceinline__ unsigned short f2bf(float f) {
    union { float f; unsigned int i; } v; v.f = f;
    unsigned int r = v.i + 0x7FFFu + ((v.i >> 16) & 1u);   // round-nearest-even
    return (unsigned short)(r >> 16);
}

__device__ __forceinline__ float wave_sum(float v) {
    #pragma unroll
    for (int off = 32; off > 0; off >>= 1) v += __shfl_xor(v, off, 64);
    return v;
}
__device__ __forceinline__ float wave_max(float v) {
    #pragma unroll
    for (int off = 32; off > 0; off >>= 1) v = fmaxf(v, __shfl_xor(v, off, 64));
    return v;
}

// ---------------------------------------------------------------------------
// Adjacency: la = relu(E E^T); top-K mask; softmax; blend with adj; diag=1;
// store un-normalized row + d_r. One wave per row.
// ---------------------------------------------------------------------------
__global__ void k_adj_row(const float* __restrict__ emb, const float* __restrict__ adj,
                          const float* __restrict__ alpha_p,
                          float* __restrict__ Araw, float* __restrict__ dvec) {
    int r = blockIdx.x;
    int lane = threadIdx.x;
    __shared__ float er[HH];
    __shared__ float la[NN];
    __shared__ float tmp[NN];
    __shared__ float keep[NN];
    er[lane] = emb[r*HH + lane];
    __syncthreads();
    for (int j = lane; j < NN; j += 64) {
        float d = 0.f;
        #pragma unroll 8
        for (int h = 0; h < HH; ++h) d += er[h] * emb[j*HH + h];
        float v = fmaxf(d, 0.f);
        la[j] = v; tmp[j] = v; keep[j] = 0.f;
    }
    __syncthreads();
    for (int it = 0; it < KK; ++it) {
        float bv = -1.f; int bi = NN;
        for (int j = lane; j < NN; j += 64) {
            float v = tmp[j];
            if (v > bv) { bv = v; bi = j; }
        }
        #pragma unroll
        for (int off = 32; off > 0; off >>= 1) {
            float ov = __shfl_xor(bv, off, 64);
            int   oi = __shfl_xor(bi, off, 64);
            if (ov > bv || (ov == bv && oi < bi)) { bv = ov; bi = oi; }
        }
        if (lane == 0) { keep[bi] = 1.f; tmp[bi] = -1.f; }
        __syncthreads();
    }
    float mloc = 0.f;
    for (int j = lane; j < NN; j += 64) {
        float v = (keep[j] > 0.f) ? la[j] : 0.f;
        tmp[j] = v;
        mloc = fmaxf(mloc, v);
    }
    float m = wave_max(mloc);
    float sloc = 0.f;
    for (int j = lane; j < NN; j += 64) sloc += expf(tmp[j] - m);
    float ssum = wave_sum(sloc);
    float alpha = alpha_p[0];
    float rloc = 0.f;
    for (int j = lane; j < NN; j += 64) {
        float soft = expf(tmp[j] - m) / ssum;
        float comb = alpha * adj[r*NN + j] + (1.f - alpha) * soft;
        float a = (j == r) ? 1.f : comb;
        Araw[r*NN + j] = a;
        rloc += a;
    }
    float rs = wave_sum(rloc);
    if (lane == 0) dvec[r] = 1.f / sqrtf(fmaxf(rs, 1.f));
}

__global__ void k_adj_scale(const float* __restrict__ Araw, const float* __restrict__ dvec,
                            float* __restrict__ Amat) {
    int r = blockIdx.x, j = threadIdx.x;
    if (j < NN) Amat[r*NN + j] = Araw[r*NN + j] * dvec[r] * dvec[j];
}

// ---------------------------------------------------------------------------
// Prep: cast tW -> bf16; build padded bf16 adjacency (208x224, zeros in pad);
// build transposed bf16 gcn weights gWT[i][n][k] = gW[i][k][n].
// ---------------------------------------------------------------------------
__global__ void k_prep(const float* __restrict__ tW, const float* __restrict__ gW,
                       const float* __restrict__ Amat, unsigned short* __restrict__ tWb,
                       unsigned short* __restrict__ Ab, unsigned short* __restrict__ gWT) {
    int i = blockIdx.x*256 + threadIdx.x;
    if (i < NBLK*SS*SS) tWb[i] = f2bf(tW[i]);
    if (i < NPAD*KPAD) {
        int m = i / KPAD, k = i % KPAD;
        Ab[i] = (m < NN && k < NN) ? f2bf(Amat[m*NN + k]) : (unsigned short)0;
    }
    if (i < NBLK*HH*HH) {
        int blk = i >> 12, r = (i >> 6) & 63, c = i & 63;
        gWT[i] = f2bf(gW[(blk << 12) + c*HH + r]);
    }
}

// ---------------------------------------------------------------------------
// Stage0: InstanceNorm over S -> proj (8->64) -> +emb. bf16 out. Wave per (b,n).
// ---------------------------------------------------------------------------
__global__ void k_stage0(const float* __restrict__ x, const float* __restrict__ inw,
                         const float* __restrict__ inb, const float* __restrict__ pW,
                         const float* __restrict__ pb, const float* __restrict__ emb,
                         unsigned short* __restrict__ X) {
    int bn = blockIdx.x;
    int lane = threadIdx.x;
    int n = bn % NN;
    __shared__ float xl[SS*FIN];
    const float* xp = x + (size_t)bn*SS*FIN;
    for (int i = lane; i < SS*FIN; i += 64) xl[i] = xp[i];
    __syncthreads();
    float sum8[FIN], sq8[FIN];
    #pragma unroll
    for (int f = 0; f < FIN; ++f) { sum8[f] = 0.f; sq8[f] = 0.f; }
    #pragma unroll
    for (int k = 0; k < 3; ++k) {
        int s = lane*3 + k;
        #pragma unroll
        for (int f = 0; f < FIN; ++f) {
            float v = xl[s*FIN + f];
            sum8[f] += v; sq8[f] += v*v;
        }
    }
    #pragma unroll
    for (int f = 0; f < FIN; ++f) { sum8[f] = wave_sum(sum8[f]); sq8[f] = wave_sum(sq8[f]); }
    float scal[FIN], bias[FIN];
    #pragma unroll
    for (int f = 0; f < FIN; ++f) {
        float mu  = sum8[f] * (1.f/SS);
        float var = sq8[f] * (1.f/SS) - mu*mu;
        float sc  = inw[f] / sqrtf(var + EPSF);
        scal[f] = sc;
        bias[f] = inb[f] - mu*sc;
    }
    float pwr[FIN];
    #pragma unroll
    for (int f = 0; f < FIN; ++f) pwr[f] = pW[f*HH + lane];
    float cst = pb[lane] + emb[n*HH + lane];
    unsigned short* op = X + (size_t)bn*SH;
    for (int s = 0; s < SS; ++s) {
        float acc = cst;
        #pragma unroll
        for (int f = 0; f < FIN; ++f) acc += (xl[s*FIN + f]*scal[f] + bias[f]) * pwr[f];
        op[s*HH + lane] = f2bf(acc);
    }
}

// ---------------------------------------------------------------------------
// Temporal MFMA (IN-PLACE): x[t,h] += gelu( W@x + tb )
// Block per (b,n). xT (transposed x) in LDS; W-frags direct from global (L2-hot).
// Wave w handles t-tiles {3w,3w+1,3w+2} x all 4 h-tiles.
// ---------------------------------------------------------------------------
#define TPITCH 200
__global__ __launch_bounds__(256) void k_temporal_mfma(unsigned short* __restrict__ X,
        const unsigned short* __restrict__ Wb, const float* __restrict__ tb) {
    __shared__ unsigned short xT[HH * TPITCH];   // 25.6 KB
    int bn = blockIdx.x, tid = threadIdx.x;
    unsigned short* xp = X + (size_t)bn*SH;
    const unsigned int* xp32 = (const unsigned int*)xp;
    for (int i = tid; i < SH/2; i += 256) {
        unsigned int u = xp32[i];
        int s = i >> 5, hp = i & 31;
        xT[(2*hp)*TPITCH + s]   = (unsigned short)(u & 0xffffu);
        xT[(2*hp+1)*TPITCH + s] = (unsigned short)(u >> 16);
    }
    __syncthreads();
    int lane = tid & 63, w = tid >> 6;
    int col = lane & 15, q = lane >> 4;
    f32x4 acc[3][4];
    #pragma unroll
    for (int tt = 0; tt < 3; ++tt)
        #pragma unroll
        for (int ht = 0; ht < 4; ++ht) acc[tt][ht] = (f32x4){0.f,0.f,0.f,0.f};

    #pragma unroll 2
    for (int k0 = 0; k0 < SS; k0 += 32) {
        bf16x8 a[3], b[4];
        #pragma unroll
        for (int tt = 0; tt < 3; ++tt)
            a[tt] = *(const bf16x8*)(Wb + (size_t)(w*48 + tt*16 + col)*SS + k0 + q*8);
        #pragma unroll
        for (int ht = 0; ht < 4; ++ht)
            b[ht] = *(const bf16x8*)(&xT[(ht*16 + col)*TPITCH + k0 + q*8]);
        #pragma unroll
        for (int tt = 0; tt < 3; ++tt)
            #pragma unroll
            for (int ht = 0; ht < 4; ++ht)
                acc[tt][ht] = __builtin_amdgcn_mfma_f32_16x16x32_bf16(a[tt], b[ht], acc[tt][ht], 0, 0, 0);
    }
    #pragma unroll
    for (int tt = 0; tt < 3; ++tt) {
        int t0 = w*48 + tt*16 + q*4;
        float tbv[4];
        #pragma unroll
        for (int r = 0; r < 4; ++r) tbv[r] = tb[t0 + r];
        #pragma unroll
        for (int ht = 0; ht < 4; ++ht) {
            int h = ht*16 + col;
            const unsigned short* rp = &xT[h*TPITCH + t0];   // 4 consecutive t (8B aligned)
            #pragma unroll
            for (int r = 0; r < 4; ++r) {
                float y = acc[tt][ht][r] + tbv[r];
                float g = 0.5f * y * (1.f + erff(y * 0.70710678118f));
                xp[(t0 + r)*HH + h] = f2bf(bf2f(rp[r]) + g);
            }
        }
    }
}

// ---------------------------------------------------------------------------
// Spatial1 MFMA (per s-chunk): z[b,node,c] = sum_n A[node,n] x[b,n,colbase+c]
// Operand swap: D[m=c][n=node], A-op = x^T (LDS), B-op = adjacency rows (global).
// Block: 64 c-columns (wave w -> c-tile w), all 13 node-tiles, K=224 padded.
// ---------------------------------------------------------------------------
#define PK 232
__global__ __launch_bounds__(256) void k_spatial1_mfma(const unsigned short* __restrict__ X,
        const unsigned short* __restrict__ Ab, unsigned short* __restrict__ Z, int colbase) {
    __shared__ unsigned short xT[64 * PK];   // 29.7 KB
    int c0 = blockIdx.x * 64, b = blockIdx.y, tid = threadIdx.x;
    const unsigned int* xp32 = (const unsigned int*)(X + (size_t)b*NN*SH + colbase + c0);
    for (int i = tid; i < NN*32; i += 256) {
        int n = i >> 5, cp = i & 31;
        unsigned int u = xp32[(size_t)n*(SH/2) + cp];
        xT[(2*cp)*PK + n]   = (unsigned short)(u & 0xffffu);
        xT[(2*cp+1)*PK + n] = (unsigned short)(u >> 16);
    }
    for (int i = tid; i < 64*(KPAD-NN); i += 256)
        xT[(i/(KPAD-NN))*PK + NN + (i%(KPAD-NN))] = 0;   // zero K-pad (avoid 0*NaN)
    __syncthreads();
    int lane = tid & 63, w = tid >> 6;
    int col = lane & 15, q = lane >> 4;
    f32x4 acc[13];
    #pragma unroll
    for (int nt = 0; nt < 13; ++nt) acc[nt] = (f32x4){0.f,0.f,0.f,0.f};
    for (int k0 = 0; k0 < KPAD; k0 += 32) {
        bf16x8 a = *(const bf16x8*)(&xT[(w*16 + col)*PK + k0 + q*8]);
        #pragma unroll
        for (int nt = 0; nt < 13; ++nt) {
            bf16x8 bfr = *(const bf16x8*)(Ab + (size_t)(nt*16 + col)*KPAD + k0 + q*8);
            acc[nt] = __builtin_amdgcn_mfma_f32_16x16x32_bf16(a, bfr, acc[nt], 0, 0, 0);
        }
    }
    int c = c0 + w*16 + q*4;
    #pragma unroll
    for (int nt = 0; nt < 13; ++nt) {
        int node = nt*16 + col;
        if (node < NN) {
            unsigned long long pk =
                  (unsigned long long)f2bf(acc[nt][0])
                | ((unsigned long long)f2bf(acc[nt][1]) << 16)
                | ((unsigned long long)f2bf(acc[nt][2]) << 32)
                | ((unsigned long long)f2bf(acc[nt][3]) << 48);
            *(unsigned long long*)(Z + ((size_t)b*NN + node)*CCH + c) = pk;
        }
    }
}

// ---------------------------------------------------------------------------
// Spatial2 MFMA (per s-chunk, IN-PLACE on X):
//   x = LN_h( x + z @ gcn_W + gcn_b ) * ln_w + ln_b
// One wave per (b,node). A-op = z rows (global, contiguous h), B-op = gWT.
// LN reduction: sum across 4 n-tiles in-register + xor-shuffle over low 4 bits.
// ---------------------------------------------------------------------------
__global__ __launch_bounds__(64) void k_spatial2_mfma(unsigned short* __restrict__ X,
        const unsigned short* __restrict__ Z, const unsigned short* __restrict__ WT,
        const float* __restrict__ gb, const float* __restrict__ lnw,
        const float* __restrict__ lnb, int s0) {
    int bm = blockIdx.x;
    int lane = threadIdx.x;
    int col = lane & 15, q = lane >> 4;
    const unsigned short* zp = Z + (size_t)bm*CCH;
    f32x4 acc[3][4];
    #pragma unroll
    for (int mt = 0; mt < 3; ++mt)
        #pragma unroll
        for (int nt = 0; nt < 4; ++nt) acc[mt][nt] = (f32x4){0.f,0.f,0.f,0.f};
    #pragma unroll
    for (int k0 = 0; k0 < HH; k0 += 32) {
        bf16x8 a[3], bfr[4];
        #pragma unroll
        for (int mt = 0; mt < 3; ++mt)
            a[mt] = *(const bf16x8*)(zp + (mt*16 + col)*HH + k0 + q*8);
        #pragma unroll
        for (int nt = 0; nt < 4; ++nt)
            bfr[nt] = *(const bf16x8*)(WT + (nt*16 + col)*HH + k0 + q*8);
        #pragma unroll
        for (int mt = 0; mt < 3; ++mt)
            #pragma unroll
            for (int nt = 0; nt < 4; ++nt)
                acc[mt][nt] = __builtin_amdgcn_mfma_f32_16x16x32_bf16(a[mt], bfr[nt], acc[mt][nt], 0, 0, 0);
    }
    unsigned short* xp = X + (size_t)bm*SH + s0*HH;
    float gbv[4], lwv[4], lbv[4];
    #pragma unroll
    for (int nt = 0; nt < 4; ++nt) {
        int h = nt*16 + col;
        gbv[nt] = gb[h]; lwv[nt] = lnw[h]; lbv[nt] = lnb[h];
    }
    #pragma unroll
    for (int mt = 0; mt < 3; ++mt) {
        float v[4][4];
        float sv[4] = {0.f,0.f,0.f,0.f}, sq[4] = {0.f,0.f,0.f,0.f};
        #pragma unroll
        for (int nt = 0; nt < 4; ++nt) {
            int h = nt*16 + col;
            #pragma unroll
            for (int r = 0; r < 4; ++r) {
                int row = mt*16 + q*4 + r;
                float t = acc[mt][nt][r] + bf2f(xp[row*HH + h]) + gbv[nt];
                v[nt][r] = t; sv[r] += t; sq[r] += t*t;
            }
        }
        #pragma unroll
        for (int r = 0; r < 4; ++r) {
            #pragma unroll
            for (int off = 1; off < 16; off <<= 1) {
                sv[r] += __shfl_xor(sv[r], off, 64);
                sq[r] += __shfl_xor(sq[r], off, 64);
            }
        }
        #pragma unroll
        for (int nt = 0; nt < 4; ++nt) {
            int h = nt*16 + col;
            #pragma unroll
            for (int r = 0; r < 4; ++r) {
                float mu  = sv[r] * (1.f/64.f);
                float var = sq[r] * (1.f/64.f) - mu*mu;
                float o = (v[nt][r] - mu) * (1.f / sqrtf(var + EPSF)) * lwv[nt] + lbv[nt];
                int row = mt*16 + q*4 + r;
                xp[row*HH + h] = f2bf(o);
            }
        }
    }
}

// ---------------------------------------------------------------------------
// Head: out[row,p] = concat(x_hist, x_futr)[row,:] @ head_W + head_b
// 32 rows x 48 p per block, 4-way split-K over 15360, atomicAdd combine.
// ---------------------------------------------------------------------------
__global__ __launch_bounds__(192) void k_head(const unsigned short* __restrict__ Xf,
        const float* __restrict__ xfut, const float* __restrict__ fW,
        const float* __restrict__ fb, const float* __restrict__ hW,
        const float* __restrict__ hb, float* __restrict__ out) {
    __shared__ float Wl[64*PP];
    __shared__ float ft[32*64];
    int ct = blockIdx.x, rt = blockIdx.y;
    int tid = threadIdx.x;
    int p = tid % PP, mq = tid / PP;
    int r0 = rt*32, c0 = ct*3840;
    float acc[8];
    #pragma unroll
    for (int j = 0; j < 8; ++j) acc[j] = (ct == 0) ? hb[p] : 0.f;
    for (int cc0 = 0; cc0 < 3840; cc0 += 64) {
        int cg = c0 + cc0;
        for (int i = tid; i < 64*PP; i += 192) Wl[i] = hW[(size_t)cg*PP + i];
        for (int i = tid; i < 2048; i += 192) {
            int mi = i >> 6, ccc = i & 63;
            int row = r0 + mi, cglob = cg + ccc;
            float v;
            if (cglob < SH) {
                v = bf2f(Xf[(size_t)row*SH + cglob]);
            } else {
                int cp = cglob - SH, ppp = cp >> 6, hh = cp & 63;
                v = fb[hh];
                #pragma unroll
                for (int f = 0; f < FNN; ++f)
                    v += xfut[((size_t)row*PP + ppp)*FNN + f] * fW[f*HH + hh];
            }
            ft[i] = v;
        }
        __syncthreads();
        #pragma unroll 4
        for (int ccc = 0; ccc < 64; ++ccc) {
            float w = Wl[ccc*PP + p];
            #pragma unroll
            for (int j = 0; j < 8; ++j) acc[j] += ft[(mq*8 + j)*64 + ccc] * w;
        }
        __syncthreads();
    }
    #pragma unroll
    for (int j = 0; j < 8; ++j)
        atomicAdd(&out[(size_t)(r0 + mq*8 + j)*PP + p], acc[j]);
}

// ---------------------------------------------------------------------------
extern "C" void kernel_launch(void* const* d_in, const int* in_sizes, int n_in,
                              void* d_out, int out_size, void* d_ws, size_t ws_size,
                              hipStream_t stream) {
    const float* x     = (const float*)d_in[0];
    const float* xfut  = (const float*)d_in[1];
    const float* adj   = (const float*)d_in[2];
    const float* emb   = (const float*)d_in[3];
    const float* alpha = (const float*)d_in[4];
    const float* inw   = (const float*)d_in[5];
    const float* inb   = (const float*)d_in[6];
    const float* pW    = (const float*)d_in[7];
    const float* pb    = (const float*)d_in[8];
    const float* tW    = (const float*)d_in[9];
    const float* tb    = (const float*)d_in[10];
    const float* gW    = (const float*)d_in[11];
    const float* gb    = (const float*)d_in[12];
    const float* lnw   = (const float*)d_in[13];
    const float* lnb   = (const float*)d_in[14];
    const float* fW    = (const float*)d_in[15];
    const float* fb    = (const float*)d_in[16];
    const float* hW    = (const float*)d_in[17];
    const float* hb    = (const float*)d_in[18];
    float* out = (float*)d_out;

    // Workspace layout (~197.3 MB):
    //   bufX (bf16 X)            157.3 MB
    //   bufZ (bf16 z chunk)       39.3 MB
    //   Amat/Araw/dvec fp32        0.32 MB
    //   tWb/Ab/gWT bf16            0.34 MB
    unsigned short* bufX = (unsigned short*)d_ws;
    unsigned short* bufZ = bufX + XSZ;
    float* Amat = (float*)(bufZ + (size_t)BB*NN*CCH);
    float* Araw = Amat + NN*NN;
    float* dvec = Araw + NN*NN;
    unsigned short* tWb = (unsigned short*)(dvec + NN);
    unsigned short* Ab  = tWb + NBLK*SS*SS;
    unsigned short* gWT = Ab + NPAD*KPAD;

    hipMemsetAsync(d_out, 0, (size_t)ROWS*PP*sizeof(float), stream);
    k_adj_row<<<NN, 64, 0, stream>>>(emb, adj, alpha, Araw, dvec);
    k_adj_scale<<<NN, 256, 0, stream>>>(Araw, dvec, Amat);
    k_prep<<<(NBLK*SS*SS + 255)/256, 256, 0, stream>>>(tW, gW, Amat, tWb, Ab, gWT);
    k_stage0<<<ROWS, 64, 0, stream>>>(x, inw, inb, pW, pb, emb, bufX);

    for (int i = 0; i < NBLK; ++i) {
        k_temporal_mfma<<<ROWS, 256, 0, stream>>>(bufX, tWb + (size_t)i*SS*SS, tb + i*SS);
        for (int ch = 0; ch < NCH; ++ch) {
            k_spatial1_mfma<<<dim3(CCH/64, BB), 256, 0, stream>>>(bufX, Ab, bufZ, ch*CCH);
            k_spatial2_mfma<<<ROWS, 64, 0, stream>>>(bufX, bufZ, gWT + (size_t)i*HH*HH,
                                                     gb + i*HH, lnw + i*HH, lnb + i*HH, ch*SCH);
        }
    }
    k_head<<<dim3(4, 200), 192, 0, stream>>>(bufX, xfut, fW, fb, hW, hb, out);
}

// Round 4
// 1776.547 us; speedup vs baseline: 4.3579x; 1.2207x over previous
//
#include <hip/hip_runtime.h>
#include <math.h>

// Problem constants
#define BB   32
#define NN   200
#define SS   192
#define FIN  8
#define HH   64
#define PP   48
#define FNN  4
#define KK   10
#define NBLK 3
#define EPSF 1e-5f
#define SH   (SS*HH)               // 12288
#define XSZ  ((size_t)BB*NN*SS*HH) // 78,643,200 elements
#define ROWS (BB*NN)               // 6400
#define SCH  48                    // s-chunk for spatial z
#define NCH  (SS/SCH)              // 4 chunks
#define CCH  (SCH*HH)              // 3072 cols per chunk
#define NPAD 208                   // node dim padded (N of spatial1)
#define KPAD 224                   // node contraction padded (K of spatial1)

typedef __attribute__((ext_vector_type(8))) short bf16x8;
typedef __attribute__((ext_vector_type(4))) float f32x4;

// bf16 <-> f32 helpers on raw ushort storage
__device__ __forceinline__ float bf2f(unsigned short u) {
    union { unsigned int i; float f; } v; v.i = ((unsigned int)u) << 16; return v.f;
}
__device__ __forceinline__ unsigned short f2bf(float f) {
    union { float f; unsigned int i; } v; v.f = f;
    unsigned int r = v.i + 0x7FFFu + ((v.i >> 16) & 1u);   // round-nearest-even
    return (unsigned short)(r >> 16);
}

__device__ __forceinline__ float wave_sum(float v) {
    #pragma unroll
    for (int off = 32; off > 0; off >>= 1) v += __shfl_xor(v, off, 64);
    return v;
}
__device__ __forceinline__ float wave_max(float v) {
    #pragma unroll
    for (int off = 32; off > 0; off >>= 1) v = fmaxf(v, __shfl_xor(v, off, 64));
    return v;
}

// ---------------------------------------------------------------------------
// Adjacency: la = relu(E E^T); top-K mask; softmax; blend with adj; diag=1;
// store un-normalized row + d_r. One wave per row.
// ---------------------------------------------------------------------------
__global__ void k_adj_row(const float* __restrict__ emb, const float* __restrict__ adj,
                          const float* __restrict__ alpha_p,
                          float* __restrict__ Araw, float* __restrict__ dvec) {
    int r = blockIdx.x;
    int lane = threadIdx.x;
    __shared__ float er[HH];
    __shared__ float la[NN];
    __shared__ float tmp[NN];
    __shared__ float keep[NN];
    er[lane] = emb[r*HH + lane];
    __syncthreads();
    for (int j = lane; j < NN; j += 64) {
        float d = 0.f;
        #pragma unroll 8
        for (int h = 0; h < HH; ++h) d += er[h] * emb[j*HH + h];
        float v = fmaxf(d, 0.f);
        la[j] = v; tmp[j] = v; keep[j] = 0.f;
    }
    __syncthreads();
    for (int it = 0; it < KK; ++it) {
        float bv = -1.f; int bi = NN;
        for (int j = lane; j < NN; j += 64) {
            float v = tmp[j];
            if (v > bv) { bv = v; bi = j; }
        }
        #pragma unroll
        for (int off = 32; off > 0; off >>= 1) {
            float ov = __shfl_xor(bv, off, 64);
            int   oi = __shfl_xor(bi, off, 64);
            if (ov > bv || (ov == bv && oi < bi)) { bv = ov; bi = oi; }
        }
        if (lane == 0) { keep[bi] = 1.f; tmp[bi] = -1.f; }
        __syncthreads();
    }
    float mloc = 0.f;
    for (int j = lane; j < NN; j += 64) {
        float v = (keep[j] > 0.f) ? la[j] : 0.f;
        tmp[j] = v;
        mloc = fmaxf(mloc, v);
    }
    float m = wave_max(mloc);
    float sloc = 0.f;
    for (int j = lane; j < NN; j += 64) sloc += expf(tmp[j] - m);
    float ssum = wave_sum(sloc);
    float alpha = alpha_p[0];
    float rloc = 0.f;
    for (int j = lane; j < NN; j += 64) {
        float soft = expf(tmp[j] - m) / ssum;
        float comb = alpha * adj[r*NN + j] + (1.f - alpha) * soft;
        float a = (j == r) ? 1.f : comb;
        Araw[r*NN + j] = a;
        rloc += a;
    }
    float rs = wave_sum(rloc);
    if (lane == 0) dvec[r] = 1.f / sqrtf(fmaxf(rs, 1.f));
}

__global__ void k_adj_scale(const float* __restrict__ Araw, const float* __restrict__ dvec,
                            float* __restrict__ Amat) {
    int r = blockIdx.x, j = threadIdx.x;
    if (j < NN) Amat[r*NN + j] = Araw[r*NN + j] * dvec[r] * dvec[j];
}

// ---------------------------------------------------------------------------
// Prep: cast tW -> bf16; build padded bf16 adjacency (208x224, zeros in pad);
// build transposed bf16 gcn weights gWT[i][n][k] = gW[i][k][n].
// ---------------------------------------------------------------------------
__global__ void k_prep(const float* __restrict__ tW, const float* __restrict__ gW,
                       const float* __restrict__ Amat, unsigned short* __restrict__ tWb,
                       unsigned short* __restrict__ Ab, unsigned short* __restrict__ gWT) {
    int i = blockIdx.x*256 + threadIdx.x;
    if (i < NBLK*SS*SS) tWb[i] = f2bf(tW[i]);
    if (i < NPAD*KPAD) {
        int m = i / KPAD, k = i % KPAD;
        Ab[i] = (m < NN && k < NN) ? f2bf(Amat[m*NN + k]) : (unsigned short)0;
    }
    if (i < NBLK*HH*HH) {
        int blk = i >> 12, r = (i >> 6) & 63, c = i & 63;
        gWT[i] = f2bf(gW[(blk << 12) + c*HH + r]);
    }
}

// ---------------------------------------------------------------------------
// Prep2 (head): hWT[n][k] = bf16(head_W[k][n]) for k < SH;
//   C1[j=p2*4+f][p] = sum_h fW[f,h]*hW[SH+p2*64+h][p]   (futr branch folded)
//   c0[p] = hb[p] + sum_{p2,h} fb[h]*hW[SH+p2*64+h][p]
// ---------------------------------------------------------------------------
__global__ void k_prep2(const float* __restrict__ hW, const float* __restrict__ fW,
                        const float* __restrict__ fb, const float* __restrict__ hb,
                        unsigned short* __restrict__ hWT, float* __restrict__ C1,
                        float* __restrict__ c0) {
    int i = blockIdx.x*256 + threadIdx.x;
    if (i < PP*SH) {
        int n = i / SH, k = i % SH;
        hWT[i] = f2bf(hW[(size_t)k*PP + n]);
    }
    if (i < PP*FNN*PP) {            // 192*48
        int j = i / PP, p = i % PP;
        int p2 = j >> 2, f = j & 3;
        float s = 0.f;
        #pragma unroll 8
        for (int h = 0; h < HH; ++h)
            s += fW[f*HH + h] * hW[(size_t)(SH + p2*HH + h)*PP + p];
        C1[i] = s;
    }
    if (i < PP) {
        float s = hb[i];
        for (int c = 0; c < PP*HH; ++c)
            s += fb[c & 63] * hW[(size_t)(SH + c)*PP + i];
        c0[i] = s;
    }
}

// ---------------------------------------------------------------------------
// Stage0: InstanceNorm over S -> proj (8->64) -> +emb. bf16 out. Wave per (b,n).
// ---------------------------------------------------------------------------
__global__ void k_stage0(const float* __restrict__ x, const float* __restrict__ inw,
                         const float* __restrict__ inb, const float* __restrict__ pW,
                         const float* __restrict__ pb, const float* __restrict__ emb,
                         unsigned short* __restrict__ X) {
    int bn = blockIdx.x;
    int lane = threadIdx.x;
    int n = bn % NN;
    __shared__ float xl[SS*FIN];
    const float* xp = x + (size_t)bn*SS*FIN;
    for (int i = lane; i < SS*FIN; i += 64) xl[i] = xp[i];
    __syncthreads();
    float sum8[FIN], sq8[FIN];
    #pragma unroll
    for (int f = 0; f < FIN; ++f) { sum8[f] = 0.f; sq8[f] = 0.f; }
    #pragma unroll
    for (int k = 0; k < 3; ++k) {
        int s = lane*3 + k;
        #pragma unroll
        for (int f = 0; f < FIN; ++f) {
            float v = xl[s*FIN + f];
            sum8[f] += v; sq8[f] += v*v;
        }
    }
    #pragma unroll
    for (int f = 0; f < FIN; ++f) { sum8[f] = wave_sum(sum8[f]); sq8[f] = wave_sum(sq8[f]); }
    float scal[FIN], bias[FIN];
    #pragma unroll
    for (int f = 0; f < FIN; ++f) {
        float mu  = sum8[f] * (1.f/SS);
        float var = sq8[f] * (1.f/SS) - mu*mu;
        float sc  = inw[f] / sqrtf(var + EPSF);
        scal[f] = sc;
        bias[f] = inb[f] - mu*sc;
    }
    float pwr[FIN];
    #pragma unroll
    for (int f = 0; f < FIN; ++f) pwr[f] = pW[f*HH + lane];
    float cst = pb[lane] + emb[n*HH + lane];
    unsigned short* op = X + (size_t)bn*SH;
    for (int s = 0; s < SS; ++s) {
        float acc = cst;
        #pragma unroll
        for (int f = 0; f < FIN; ++f) acc += (xl[s*FIN + f]*scal[f] + bias[f]) * pwr[f];
        op[s*HH + lane] = f2bf(acc);
    }
}

// ---------------------------------------------------------------------------
// Temporal MFMA (IN-PLACE): x[t,h] += gelu( W@x + tb )
// Block per (b,n). xT (transposed x) in LDS; W-frags direct from global (L2-hot).
// ---------------------------------------------------------------------------
#define TPITCH 200
__global__ __launch_bounds__(256) void k_temporal_mfma(unsigned short* __restrict__ X,
        const unsigned short* __restrict__ Wb, const float* __restrict__ tb) {
    __shared__ unsigned short xT[HH * TPITCH];   // 25.6 KB
    int bn = blockIdx.x, tid = threadIdx.x;
    unsigned short* xp = X + (size_t)bn*SH;
    const unsigned int* xp32 = (const unsigned int*)xp;
    for (int i = tid; i < SH/2; i += 256) {
        unsigned int u = xp32[i];
        int s = i >> 5, hp = i & 31;
        xT[(2*hp)*TPITCH + s]   = (unsigned short)(u & 0xffffu);
        xT[(2*hp+1)*TPITCH + s] = (unsigned short)(u >> 16);
    }
    __syncthreads();
    int lane = tid & 63, w = tid >> 6;
    int col = lane & 15, q = lane >> 4;
    f32x4 acc[3][4];
    #pragma unroll
    for (int tt = 0; tt < 3; ++tt)
        #pragma unroll
        for (int ht = 0; ht < 4; ++ht) acc[tt][ht] = (f32x4){0.f,0.f,0.f,0.f};

    #pragma unroll 2
    for (int k0 = 0; k0 < SS; k0 += 32) {
        bf16x8 a[3], b[4];
        #pragma unroll
        for (int tt = 0; tt < 3; ++tt)
            a[tt] = *(const bf16x8*)(Wb + (size_t)(w*48 + tt*16 + col)*SS + k0 + q*8);
        #pragma unroll
        for (int ht = 0; ht < 4; ++ht)
            b[ht] = *(const bf16x8*)(&xT[(ht*16 + col)*TPITCH + k0 + q*8]);
        #pragma unroll
        for (int tt = 0; tt < 3; ++tt)
            #pragma unroll
            for (int ht = 0; ht < 4; ++ht)
                acc[tt][ht] = __builtin_amdgcn_mfma_f32_16x16x32_bf16(a[tt], b[ht], acc[tt][ht], 0, 0, 0);
    }
    #pragma unroll
    for (int tt = 0; tt < 3; ++tt) {
        int t0 = w*48 + tt*16 + q*4;
        float tbv[4];
        #pragma unroll
        for (int r = 0; r < 4; ++r) tbv[r] = tb[t0 + r];
        #pragma unroll
        for (int ht = 0; ht < 4; ++ht) {
            int h = ht*16 + col;
            const unsigned short* rp = &xT[h*TPITCH + t0];
            #pragma unroll
            for (int r = 0; r < 4; ++r) {
                float y = acc[tt][ht][r] + tbv[r];
                float g = 0.5f * y * (1.f + erff(y * 0.70710678118f));
                xp[(t0 + r)*HH + h] = f2bf(bf2f(rp[r]) + g);
            }
        }
    }
}

// ---------------------------------------------------------------------------
// Spatial1 MFMA (per s-chunk): z[b,node,c] = sum_n A[node,n] x[b,n,colbase+c]
// Operand swap: A-op = x^T (LDS), B-op = adjacency rows (global).
// ---------------------------------------------------------------------------
#define PK 232
__global__ __launch_bounds__(256) void k_spatial1_mfma(const unsigned short* __restrict__ X,
        const unsigned short* __restrict__ Ab, unsigned short* __restrict__ Z, int colbase) {
    __shared__ unsigned short xT[64 * PK];   // 29.7 KB
    int c0 = blockIdx.x * 64, b = blockIdx.y, tid = threadIdx.x;
    const unsigned int* xp32 = (const unsigned int*)(X + (size_t)b*NN*SH + colbase + c0);
    for (int i = tid; i < NN*32; i += 256) {
        int n = i >> 5, cp = i & 31;
        unsigned int u = xp32[(size_t)n*(SH/2) + cp];
        xT[(2*cp)*PK + n]   = (unsigned short)(u & 0xffffu);
        xT[(2*cp+1)*PK + n] = (unsigned short)(u >> 16);
    }
    for (int i = tid; i < 64*(KPAD-NN); i += 256)
        xT[(i/(KPAD-NN))*PK + NN + (i%(KPAD-NN))] = 0;
    __syncthreads();
    int lane = tid & 63, w = tid >> 6;
    int col = lane & 15, q = lane >> 4;
    f32x4 acc[13];
    #pragma unroll
    for (int nt = 0; nt < 13; ++nt) acc[nt] = (f32x4){0.f,0.f,0.f,0.f};
    for (int k0 = 0; k0 < KPAD; k0 += 32) {
        bf16x8 a = *(const bf16x8*)(&xT[(w*16 + col)*PK + k0 + q*8]);
        #pragma unroll
        for (int nt = 0; nt < 13; ++nt) {
            bf16x8 bfr = *(const bf16x8*)(Ab + (size_t)(nt*16 + col)*KPAD + k0 + q*8);
            acc[nt] = __builtin_amdgcn_mfma_f32_16x16x32_bf16(a, bfr, acc[nt], 0, 0, 0);
        }
    }
    int c = c0 + w*16 + q*4;
    #pragma unroll
    for (int nt = 0; nt < 13; ++nt) {
        int node = nt*16 + col;
        if (node < NN) {
            unsigned long long pk =
                  (unsigned long long)f2bf(acc[nt][0])
                | ((unsigned long long)f2bf(acc[nt][1]) << 16)
                | ((unsigned long long)f2bf(acc[nt][2]) << 32)
                | ((unsigned long long)f2bf(acc[nt][3]) << 48);
            *(unsigned long long*)(Z + ((size_t)b*NN + node)*CCH + c) = pk;
        }
    }
}

// ---------------------------------------------------------------------------
// Spatial2 MFMA (per s-chunk, IN-PLACE on X):
//   x = LN_h( x + z @ gcn_W + gcn_b ) * ln_w + ln_b
// One wave per (b,node).
// ---------------------------------------------------------------------------
__global__ __launch_bounds__(64) void k_spatial2_mfma(unsigned short* __restrict__ X,
        const unsigned short* __restrict__ Z, const unsigned short* __restrict__ WT,
        const float* __restrict__ gb, const float* __restrict__ lnw,
        const float* __restrict__ lnb, int s0) {
    int bm = blockIdx.x;
    int lane = threadIdx.x;
    int col = lane & 15, q = lane >> 4;
    const unsigned short* zp = Z + (size_t)bm*CCH;
    f32x4 acc[3][4];
    #pragma unroll
    for (int mt = 0; mt < 3; ++mt)
        #pragma unroll
        for (int nt = 0; nt < 4; ++nt) acc[mt][nt] = (f32x4){0.f,0.f,0.f,0.f};
    #pragma unroll
    for (int k0 = 0; k0 < HH; k0 += 32) {
        bf16x8 a[3], bfr[4];
        #pragma unroll
        for (int mt = 0; mt < 3; ++mt)
            a[mt] = *(const bf16x8*)(zp + (mt*16 + col)*HH + k0 + q*8);
        #pragma unroll
        for (int nt = 0; nt < 4; ++nt)
            bfr[nt] = *(const bf16x8*)(WT + (nt*16 + col)*HH + k0 + q*8);
        #pragma unroll
        for (int mt = 0; mt < 3; ++mt)
            #pragma unroll
            for (int nt = 0; nt < 4; ++nt)
                acc[mt][nt] = __builtin_amdgcn_mfma_f32_16x16x32_bf16(a[mt], bfr[nt], acc[mt][nt], 0, 0, 0);
    }
    unsigned short* xp = X + (size_t)bm*SH + s0*HH;
    float gbv[4], lwv[4], lbv[4];
    #pragma unroll
    for (int nt = 0; nt < 4; ++nt) {
        int h = nt*16 + col;
        gbv[nt] = gb[h]; lwv[nt] = lnw[h]; lbv[nt] = lnb[h];
    }
    #pragma unroll
    for (int mt = 0; mt < 3; ++mt) {
        float v[4][4];
        float sv[4] = {0.f,0.f,0.f,0.f}, sq[4] = {0.f,0.f,0.f,0.f};
        #pragma unroll
        for (int nt = 0; nt < 4; ++nt) {
            int h = nt*16 + col;
            #pragma unroll
            for (int r = 0; r < 4; ++r) {
                int row = mt*16 + q*4 + r;
                float t = acc[mt][nt][r] + bf2f(xp[row*HH + h]) + gbv[nt];
                v[nt][r] = t; sv[r] += t; sq[r] += t*t;
            }
        }
        #pragma unroll
        for (int r = 0; r < 4; ++r) {
            #pragma unroll
            for (int off = 1; off < 16; off <<= 1) {
                sv[r] += __shfl_xor(sv[r], off, 64);
                sq[r] += __shfl_xor(sq[r], off, 64);
            }
        }
        #pragma unroll
        for (int nt = 0; nt < 4; ++nt) {
            int h = nt*16 + col;
            #pragma unroll
            for (int r = 0; r < 4; ++r) {
                float mu  = sv[r] * (1.f/64.f);
                float var = sq[r] * (1.f/64.f) - mu*mu;
                float o = (v[nt][r] - mu) * (1.f / sqrtf(var + EPSF)) * lwv[nt] + lbv[nt];
                int row = mt*16 + q*4 + r;
                xp[row*HH + h] = f2bf(o);
            }
        }
    }
}

// ---------------------------------------------------------------------------
// Head futr+bias: out[row,p] = c0[p] + xfut[row,:192] @ C1   (plain writes,
// runs BEFORE k_head_mfma which atomically accumulates the hist GEMM)
// ---------------------------------------------------------------------------
__global__ __launch_bounds__(192) void k_head_futr(const float* __restrict__ xfut,
        const float* __restrict__ C1, const float* __restrict__ c0,
        float* __restrict__ out) {
    __shared__ float C1l[192*PP];   // 36.8 KB
    __shared__ float xfl[4*192];    // 3 KB
    int tid = threadIdx.x;
    int r0 = blockIdx.x * 4;
    for (int i = tid; i < 192*PP; i += 192) C1l[i] = C1[i];
    for (int i = tid; i < 4*192; i += 192) xfl[i] = xfut[(size_t)r0*192 + i];
    __syncthreads();
    int p = tid % PP, rr = tid / PP;
    float acc = c0[p];
    #pragma unroll 8
    for (int j = 0; j < 192; ++j) acc += xfl[rr*192 + j] * C1l[j*PP + p];
    out[(size_t)(r0 + rr)*PP + p] = acc;
}

// ---------------------------------------------------------------------------
// Head hist GEMM (bf16 MFMA): out[row,p] += X[row,:12288] @ hWT^T
// A-op = X rows straight from global (contiguous k); B-op = hWT (L2-hot).
// Grid (100 m-blocks x 8 k-slices); block 4 waves x 16 rows; atomicAdd combine.
// ---------------------------------------------------------------------------
#define KSL 1536
__global__ __launch_bounds__(256) void k_head_mfma(const unsigned short* __restrict__ X,
        const unsigned short* __restrict__ hWT, float* __restrict__ out) {
    int tid = threadIdx.x;
    int lane = tid & 63, w = tid >> 6;
    int col = lane & 15, q = lane >> 4;
    int m0 = blockIdx.x*64 + w*16;
    int k0 = blockIdx.y*KSL;
    const unsigned short* xp = X + (size_t)(m0 + col)*SH + k0 + q*8;
    const unsigned short* wp = hWT + (size_t)col*SH + k0 + q*8;
    f32x4 acc[3];
    #pragma unroll
    for (int nt = 0; nt < 3; ++nt) acc[nt] = (f32x4){0.f,0.f,0.f,0.f};
    #pragma unroll 4
    for (int kk = 0; kk < KSL; kk += 32) {
        bf16x8 a = *(const bf16x8*)(xp + kk);
        #pragma unroll
        for (int nt = 0; nt < 3; ++nt) {
            bf16x8 b = *(const bf16x8*)(wp + (size_t)nt*16*SH + kk);
            acc[nt] = __builtin_amdgcn_mfma_f32_16x16x32_bf16(a, b, acc[nt], 0, 0, 0);
        }
    }
    int orow = m0 + q*4;
    #pragma unroll
    for (int nt = 0; nt < 3; ++nt)
        #pragma unroll
        for (int r = 0; r < 4; ++r)
            atomicAdd(&out[(size_t)(orow + r)*PP + nt*16 + col], acc[nt][r]);
}

// ---------------------------------------------------------------------------
extern "C" void kernel_launch(void* const* d_in, const int* in_sizes, int n_in,
                              void* d_out, int out_size, void* d_ws, size_t ws_size,
                              hipStream_t stream) {
    const float* x     = (const float*)d_in[0];
    const float* xfut  = (const float*)d_in[1];
    const float* adj   = (const float*)d_in[2];
    const float* emb   = (const float*)d_in[3];
    const float* alpha = (const float*)d_in[4];
    const float* inw   = (const float*)d_in[5];
    const float* inb   = (const float*)d_in[6];
    const float* pW    = (const float*)d_in[7];
    const float* pb    = (const float*)d_in[8];
    const float* tW    = (const float*)d_in[9];
    const float* tb    = (const float*)d_in[10];
    const float* gW    = (const float*)d_in[11];
    const float* gb    = (const float*)d_in[12];
    const float* lnw   = (const float*)d_in[13];
    const float* lnb   = (const float*)d_in[14];
    const float* fW    = (const float*)d_in[15];
    const float* fb    = (const float*)d_in[16];
    const float* hW    = (const float*)d_in[17];
    const float* hb    = (const float*)d_in[18];
    float* out = (float*)d_out;

    // Workspace layout (~198.6 MB):
    //   bufX (bf16 X)            157.3 MB
    //   bufZ (bf16 z chunk)       39.3 MB
    //   Amat/Araw/dvec fp32        0.32 MB
    //   tWb/Ab/gWT bf16            0.34 MB
    //   hWT bf16                   1.18 MB ; C1/c0 fp32 0.04 MB
    unsigned short* bufX = (unsigned short*)d_ws;
    unsigned short* bufZ = bufX + XSZ;
    float* Amat = (float*)(bufZ + (size_t)BB*NN*CCH);
    float* Araw = Amat + NN*NN;
    float* dvec = Araw + NN*NN;
    unsigned short* tWb = (unsigned short*)(dvec + NN);
    unsigned short* Ab  = tWb + NBLK*SS*SS;
    unsigned short* gWT = Ab + NPAD*KPAD;
    unsigned short* hWT = gWT + NBLK*HH*HH;
    float* C1 = (float*)(hWT + (size_t)PP*SH);
    float* c0 = C1 + 192*PP;

    k_adj_row<<<NN, 64, 0, stream>>>(emb, adj, alpha, Araw, dvec);
    k_adj_scale<<<NN, 256, 0, stream>>>(Araw, dvec, Amat);
    k_prep<<<(NBLK*SS*SS + 255)/256, 256, 0, stream>>>(tW, gW, Amat, tWb, Ab, gWT);
    k_prep2<<<((size_t)PP*SH + 255)/256, 256, 0, stream>>>(hW, fW, fb, hb, hWT, C1, c0);
    k_stage0<<<ROWS, 64, 0, stream>>>(x, inw, inb, pW, pb, emb, bufX);

    for (int i = 0; i < NBLK; ++i) {
        k_temporal_mfma<<<ROWS, 256, 0, stream>>>(bufX, tWb + (size_t)i*SS*SS, tb + i*SS);
        for (int ch = 0; ch < NCH; ++ch) {
            k_spatial1_mfma<<<dim3(CCH/64, BB), 256, 0, stream>>>(bufX, Ab, bufZ, ch*CCH);
            k_spatial2_mfma<<<ROWS, 64, 0, stream>>>(bufX, bufZ, gWT + (size_t)i*HH*HH,
                                                     gb + i*HH, lnw + i*HH, lnb + i*HH, ch*SCH);
        }
    }
    k_head_futr<<<ROWS/4, 192, 0, stream>>>(xfut, C1, c0, out);
    k_head_mfma<<<dim3(ROWS/64, 8), 256, 0, stream>>>(bufX, hWT, out);
}

// Round 5
// 1370.164 us; speedup vs baseline: 5.6504x; 1.2966x over previous
//
#include <hip/hip_runtime.h>
#include <math.h>

// Problem constants
#define BB   32
#define NN   200
#define SS   192
#define FIN  8
#define HH   64
#define PP   48
#define FNN  4
#define KK   10
#define NBLK 3
#define EPSF 1e-5f
#define SH   (SS*HH)               // 12288
#define XSZ  ((size_t)BB*NN*SS*HH) // 78,643,200 elements
#define ROWS (BB*NN)               // 6400
#define NPAD 208                   // node dim padded
#define KPAD 224                   // node contraction padded
#define XPITCH 232                 // xT LDS pitch (16B-aligned rows)
#define ZPITCH 72                  // z LDS pitch (16B-aligned, conflict-broken)

typedef __attribute__((ext_vector_type(8))) short bf16x8;
typedef __attribute__((ext_vector_type(4))) float f32x4;

// bf16 <-> f32 helpers on raw ushort storage
__device__ __forceinline__ float bf2f(unsigned short u) {
    union { unsigned int i; float f; } v; v.i = ((unsigned int)u) << 16; return v.f;
}
__device__ __forceinline__ unsigned short f2bf(float f) {
    union { float f; unsigned int i; } v; v.f = f;
    unsigned int r = v.i + 0x7FFFu + ((v.i >> 16) & 1u);   // round-nearest-even
    return (unsigned short)(r >> 16);
}

__device__ __forceinline__ float wave_sum(float v) {
    #pragma unroll
    for (int off = 32; off > 0; off >>= 1) v += __shfl_xor(v, off, 64);
    return v;
}
__device__ __forceinline__ float wave_max(float v) {
    #pragma unroll
    for (int off = 32; off > 0; off >>= 1) v = fmaxf(v, __shfl_xor(v, off, 64));
    return v;
}

// ---------------------------------------------------------------------------
// Adjacency: la = relu(E E^T); top-K mask; softmax; blend with adj; diag=1;
// store un-normalized row + d_r. One wave per row.
// ---------------------------------------------------------------------------
__global__ void k_adj_row(const float* __restrict__ emb, const float* __restrict__ adj,
                          const float* __restrict__ alpha_p,
                          float* __restrict__ Araw, float* __restrict__ dvec) {
    int r = blockIdx.x;
    int lane = threadIdx.x;
    __shared__ float er[HH];
    __shared__ float la[NN];
    __shared__ float tmp[NN];
    __shared__ float keep[NN];
    er[lane] = emb[r*HH + lane];
    __syncthreads();
    for (int j = lane; j < NN; j += 64) {
        float d = 0.f;
        #pragma unroll 8
        for (int h = 0; h < HH; ++h) d += er[h] * emb[j*HH + h];
        float v = fmaxf(d, 0.f);
        la[j] = v; tmp[j] = v; keep[j] = 0.f;
    }
    __syncthreads();
    for (int it = 0; it < KK; ++it) {
        float bv = -1.f; int bi = NN;
        for (int j = lane; j < NN; j += 64) {
            float v = tmp[j];
            if (v > bv) { bv = v; bi = j; }
        }
        #pragma unroll
        for (int off = 32; off > 0; off >>= 1) {
            float ov = __shfl_xor(bv, off, 64);
            int   oi = __shfl_xor(bi, off, 64);
            if (ov > bv || (ov == bv && oi < bi)) { bv = ov; bi = oi; }
        }
        if (lane == 0) { keep[bi] = 1.f; tmp[bi] = -1.f; }
        __syncthreads();
    }
    float mloc = 0.f;
    for (int j = lane; j < NN; j += 64) {
        float v = (keep[j] > 0.f) ? la[j] : 0.f;
        tmp[j] = v;
        mloc = fmaxf(mloc, v);
    }
    float m = wave_max(mloc);
    float sloc = 0.f;
    for (int j = lane; j < NN; j += 64) sloc += expf(tmp[j] - m);
    float ssum = wave_sum(sloc);
    float alpha = alpha_p[0];
    float rloc = 0.f;
    for (int j = lane; j < NN; j += 64) {
        float soft = expf(tmp[j] - m) / ssum;
        float comb = alpha * adj[r*NN + j] + (1.f - alpha) * soft;
        float a = (j == r) ? 1.f : comb;
        Araw[r*NN + j] = a;
        rloc += a;
    }
    float rs = wave_sum(rloc);
    if (lane == 0) dvec[r] = 1.f / sqrtf(fmaxf(rs, 1.f));
}

__global__ void k_adj_scale(const float* __restrict__ Araw, const float* __restrict__ dvec,
                            float* __restrict__ Amat) {
    int r = blockIdx.x, j = threadIdx.x;
    if (j < NN) Amat[r*NN + j] = Araw[r*NN + j] * dvec[r] * dvec[j];
}

// ---------------------------------------------------------------------------
// Prep: cast tW -> bf16; build padded bf16 adjacency (208x224, zeros in pad);
// build transposed bf16 gcn weights gWT[i][n][k] = gW[i][k][n].
// ---------------------------------------------------------------------------
__global__ void k_prep(const float* __restrict__ tW, const float* __restrict__ gW,
                       const float* __restrict__ Amat, unsigned short* __restrict__ tWb,
                       unsigned short* __restrict__ Ab, unsigned short* __restrict__ gWT) {
    int i = blockIdx.x*256 + threadIdx.x;
    if (i < NBLK*SS*SS) tWb[i] = f2bf(tW[i]);
    if (i < NPAD*KPAD) {
        int m = i / KPAD, k = i % KPAD;
        Ab[i] = (m < NN && k < NN) ? f2bf(Amat[m*NN + k]) : (unsigned short)0;
    }
    if (i < NBLK*HH*HH) {
        int blk = i >> 12, r = (i >> 6) & 63, c = i & 63;
        gWT[i] = f2bf(gW[(blk << 12) + c*HH + r]);
    }
}

// ---------------------------------------------------------------------------
// Prep2 (head): hWT[n][k] = bf16(head_W[k][n]) for k < SH;
//   C1[j=p2*4+f][p] = sum_h fW[f,h]*hW[SH+p2*64+h][p]   (futr branch folded)
//   c0[p] = hb[p] + sum_{p2,h} fb[h]*hW[SH+p2*64+h][p]
// ---------------------------------------------------------------------------
__global__ void k_prep2(const float* __restrict__ hW, const float* __restrict__ fW,
                        const float* __restrict__ fb, const float* __restrict__ hb,
                        unsigned short* __restrict__ hWT, float* __restrict__ C1,
                        float* __restrict__ c0) {
    int i = blockIdx.x*256 + threadIdx.x;
    if (i < PP*SH) {
        int n = i / SH, k = i % SH;
        hWT[i] = f2bf(hW[(size_t)k*PP + n]);
    }
    if (i < PP*FNN*PP) {            // 192*48
        int j = i / PP, p = i % PP;
        int p2 = j >> 2, f = j & 3;
        float s = 0.f;
        #pragma unroll 8
        for (int h = 0; h < HH; ++h)
            s += fW[f*HH + h] * hW[(size_t)(SH + p2*HH + h)*PP + p];
        C1[i] = s;
    }
    if (i < PP) {
        float s = hb[i];
        for (int c = 0; c < PP*HH; ++c)
            s += fb[c & 63] * hW[(size_t)(SH + c)*PP + i];
        c0[i] = s;
    }
}

// ---------------------------------------------------------------------------
// Stage0: InstanceNorm over S -> proj (8->64) -> +emb. bf16 out. Wave per (b,n).
// ---------------------------------------------------------------------------
__global__ void k_stage0(const float* __restrict__ x, const float* __restrict__ inw,
                         const float* __restrict__ inb, const float* __restrict__ pW,
                         const float* __restrict__ pb, const float* __restrict__ emb,
                         unsigned short* __restrict__ X) {
    int bn = blockIdx.x;
    int lane = threadIdx.x;
    int n = bn % NN;
    __shared__ float xl[SS*FIN];
    const float* xp = x + (size_t)bn*SS*FIN;
    for (int i = lane; i < SS*FIN; i += 64) xl[i] = xp[i];
    __syncthreads();
    float sum8[FIN], sq8[FIN];
    #pragma unroll
    for (int f = 0; f < FIN; ++f) { sum8[f] = 0.f; sq8[f] = 0.f; }
    #pragma unroll
    for (int k = 0; k < 3; ++k) {
        int s = lane*3 + k;
        #pragma unroll
        for (int f = 0; f < FIN; ++f) {
            float v = xl[s*FIN + f];
            sum8[f] += v; sq8[f] += v*v;
        }
    }
    #pragma unroll
    for (int f = 0; f < FIN; ++f) { sum8[f] = wave_sum(sum8[f]); sq8[f] = wave_sum(sq8[f]); }
    float scal[FIN], bias[FIN];
    #pragma unroll
    for (int f = 0; f < FIN; ++f) {
        float mu  = sum8[f] * (1.f/SS);
        float var = sq8[f] * (1.f/SS) - mu*mu;
        float sc  = inw[f] / sqrtf(var + EPSF);
        scal[f] = sc;
        bias[f] = inb[f] - mu*sc;
    }
    float pwr[FIN];
    #pragma unroll
    for (int f = 0; f < FIN; ++f) pwr[f] = pW[f*HH + lane];
    float cst = pb[lane] + emb[n*HH + lane];
    unsigned short* op = X + (size_t)bn*SH;
    for (int s = 0; s < SS; ++s) {
        float acc = cst;
        #pragma unroll
        for (int f = 0; f < FIN; ++f) acc += (xl[s*FIN + f]*scal[f] + bias[f]) * pwr[f];
        op[s*HH + lane] = f2bf(acc);
    }
}

// ---------------------------------------------------------------------------
// Temporal MFMA (IN-PLACE): x[t,h] += gelu( W@x + tb )
// Block per (b,n). xT (transposed x) in LDS; W-frags direct from global (L2-hot).
// GELU via tanh-form (max dev ~3e-4 vs exact erf).
// ---------------------------------------------------------------------------
#define TPITCH 200
__global__ __launch_bounds__(256) void k_temporal_mfma(unsigned short* __restrict__ X,
        const unsigned short* __restrict__ Wb, const float* __restrict__ tb) {
    __shared__ unsigned short xT[HH * TPITCH];   // 25.6 KB
    int bn = blockIdx.x, tid = threadIdx.x;
    unsigned short* xp = X + (size_t)bn*SH;
    const unsigned int* xp32 = (const unsigned int*)xp;
    for (int i = tid; i < SH/2; i += 256) {
        unsigned int u = xp32[i];
        int s = i >> 5, hp = i & 31;
        xT[(2*hp)*TPITCH + s]   = (unsigned short)(u & 0xffffu);
        xT[(2*hp+1)*TPITCH + s] = (unsigned short)(u >> 16);
    }
    __syncthreads();
    int lane = tid & 63, w = tid >> 6;
    int col = lane & 15, q = lane >> 4;
    f32x4 acc[3][4];
    #pragma unroll
    for (int tt = 0; tt < 3; ++tt)
        #pragma unroll
        for (int ht = 0; ht < 4; ++ht) acc[tt][ht] = (f32x4){0.f,0.f,0.f,0.f};

    #pragma unroll 2
    for (int k0 = 0; k0 < SS; k0 += 32) {
        bf16x8 a[3], b[4];
        #pragma unroll
        for (int tt = 0; tt < 3; ++tt)
            a[tt] = *(const bf16x8*)(Wb + (size_t)(w*48 + tt*16 + col)*SS + k0 + q*8);
        #pragma unroll
        for (int ht = 0; ht < 4; ++ht)
            b[ht] = *(const bf16x8*)(&xT[(ht*16 + col)*TPITCH + k0 + q*8]);
        #pragma unroll
        for (int tt = 0; tt < 3; ++tt)
            #pragma unroll
            for (int ht = 0; ht < 4; ++ht)
                acc[tt][ht] = __builtin_amdgcn_mfma_f32_16x16x32_bf16(a[tt], b[ht], acc[tt][ht], 0, 0, 0);
    }
    #pragma unroll
    for (int tt = 0; tt < 3; ++tt) {
        int t0 = w*48 + tt*16 + q*4;
        float tbv[4];
        #pragma unroll
        for (int r = 0; r < 4; ++r) tbv[r] = tb[t0 + r];
        #pragma unroll
        for (int ht = 0; ht < 4; ++ht) {
            int h = ht*16 + col;
            const unsigned short* rp = &xT[h*TPITCH + t0];
            #pragma unroll
            for (int r = 0; r < 4; ++r) {
                float y = acc[tt][ht][r] + tbv[r];
                // gelu(y) ~= y * sigmoid(2*0.7978845608*(y + 0.044715 y^3))
                float u2 = y * (1.5957691216f + 0.07135481626f*y*y);
                float g = y / (1.f + __expf(-u2));
                xp[(t0 + r)*HH + h] = f2bf(bf2f(rp[r]) + g);
            }
        }
    }
}

// ---------------------------------------------------------------------------
// Fused spatial (IN-PLACE on X), block = (s', b):
//   z[node,h] = sum_n A[node,n] x[b,n,s',h]        (MFMA1, K=224)
//   y[node,h'] = z[node,:] @ gcn_W                 (MFMA2, K=64)
//   x = LN_h'( x + y + gb ) * ln_w + ln_b
// xT tile staged once in LDS serves both MFMA1 A-op and the residual.
// ---------------------------------------------------------------------------
__global__ __launch_bounds__(256) void k_spatial_fused(unsigned short* __restrict__ X,
        const unsigned short* __restrict__ Ab, const unsigned short* __restrict__ gWT,
        const float* __restrict__ gb, const float* __restrict__ lnw,
        const float* __restrict__ lnb) {
    __shared__ unsigned short xT[64 * XPITCH];   // 29.7 KB : xT[h][n]
    __shared__ unsigned short zl[NPAD * ZPITCH]; // 29.9 KB : zl[node][h]
    int sp = blockIdx.x, b = blockIdx.y, tid = threadIdx.x;
    unsigned short* xbase = X + (size_t)b*NN*SH + sp*HH;
    const unsigned int* xp32 = (const unsigned int*)xbase;
    // stage transpose: xT[h][n] = X[b][n][sp*64 + h]
    for (int i = tid; i < NN*32; i += 256) {
        int n = i >> 5, hp = i & 31;
        unsigned int u = xp32[(size_t)n*(SH/2) + hp];
        xT[(2*hp)*XPITCH + n]   = (unsigned short)(u & 0xffffu);
        xT[(2*hp+1)*XPITCH + n] = (unsigned short)(u >> 16);
    }
    for (int i = tid; i < 64*(KPAD-NN); i += 256)
        xT[(i/(KPAD-NN))*XPITCH + NN + (i%(KPAD-NN))] = 0;   // zero K-pad
    __syncthreads();
    int lane = tid & 63, w = tid >> 6;
    int col = lane & 15, q = lane >> 4;
    // MFMA1: D1[m=h (tile w)][n=node] = sum_n' xT[h][n'] * Ab[node][n']
    f32x4 acc1[13];
    #pragma unroll
    for (int nt = 0; nt < 13; ++nt) acc1[nt] = (f32x4){0.f,0.f,0.f,0.f};
    for (int k0 = 0; k0 < KPAD; k0 += 32) {
        bf16x8 a = *(const bf16x8*)(&xT[(w*16 + col)*XPITCH + k0 + q*8]);
        #pragma unroll
        for (int nt = 0; nt < 13; ++nt) {
            bf16x8 bb = *(const bf16x8*)(Ab + (size_t)(nt*16 + col)*KPAD + k0 + q*8);
            acc1[nt] = __builtin_amdgcn_mfma_f32_16x16x32_bf16(a, bb, acc1[nt], 0, 0, 0);
        }
    }
    // z write: lane holds h = w*16+q*4+{0..3} (D rows), node = nt*16+col
    #pragma unroll
    for (int nt = 0; nt < 13; ++nt) {
        unsigned long long pk =
              (unsigned long long)f2bf(acc1[nt][0])
            | ((unsigned long long)f2bf(acc1[nt][1]) << 16)
            | ((unsigned long long)f2bf(acc1[nt][2]) << 32)
            | ((unsigned long long)f2bf(acc1[nt][3]) << 48);
        *(unsigned long long*)(&zl[(nt*16 + col)*ZPITCH + w*16 + q*4]) = pk;
    }
    __syncthreads();
    // per-lane LN params at h' = nt2*16+col
    float gbv[4], lwv[4], lbv[4];
    #pragma unroll
    for (int nt2 = 0; nt2 < 4; ++nt2) {
        int h = nt2*16 + col;
        gbv[nt2] = gb[h]; lwv[nt2] = lnw[h]; lbv[nt2] = lnb[h];
    }
    // MFMA2 + LN + store; mt = node-tile
    for (int mt = w; mt < 13; mt += 4) {
        f32x4 acc2[4];
        #pragma unroll
        for (int nt2 = 0; nt2 < 4; ++nt2) acc2[nt2] = (f32x4){0.f,0.f,0.f,0.f};
        #pragma unroll
        for (int k0 = 0; k0 < HH; k0 += 32) {
            bf16x8 a = *(const bf16x8*)(&zl[(mt*16 + col)*ZPITCH + k0 + q*8]);
            #pragma unroll
            for (int nt2 = 0; nt2 < 4; ++nt2) {
                bf16x8 bw = *(const bf16x8*)(gWT + (size_t)(nt2*16 + col)*HH + k0 + q*8);
                acc2[nt2] = __builtin_amdgcn_mfma_f32_16x16x32_bf16(a, bw, acc2[nt2], 0, 0, 0);
            }
        }
        float v[4][4];
        float sv[4] = {0.f,0.f,0.f,0.f}, sq[4] = {0.f,0.f,0.f,0.f};
        #pragma unroll
        for (int nt2 = 0; nt2 < 4; ++nt2) {
            // residual x[node = mt*16+q*4+r][h' = nt2*16+col] = xT[h'][node]
            unsigned long long rr = *(const unsigned long long*)
                (&xT[(nt2*16 + col)*XPITCH + mt*16 + q*4]);
            #pragma unroll
            for (int r = 0; r < 4; ++r) {
                float t = acc2[nt2][r] + bf2f((unsigned short)(rr >> (16*r))) + gbv[nt2];
                v[nt2][r] = t; sv[r] += t; sq[r] += t*t;
            }
        }
        #pragma unroll
        for (int r = 0; r < 4; ++r) {
            #pragma unroll
            for (int off = 1; off < 16; off <<= 1) {
                sv[r] += __shfl_xor(sv[r], off, 64);
                sq[r] += __shfl_xor(sq[r], off, 64);
            }
        }
        #pragma unroll
        for (int r = 0; r < 4; ++r) {
            int node = mt*16 + q*4 + r;
            if (node < NN) {
                float mu  = sv[r] * (1.f/64.f);
                float var = sq[r] * (1.f/64.f) - mu*mu;
                float rstd = 1.f / sqrtf(var + EPSF);
                #pragma unroll
                for (int nt2 = 0; nt2 < 4; ++nt2) {
                    float o = (v[nt2][r] - mu) * rstd * lwv[nt2] + lbv[nt2];
                    xbase[(size_t)node*SH + nt2*16 + col] = f2bf(o);
                }
            }
        }
    }
}

// ---------------------------------------------------------------------------
// Head futr+bias: out[row,p] = c0[p] + xfut[row,:192] @ C1   (plain writes,
// runs BEFORE k_head_mfma which atomically accumulates the hist GEMM)
// ---------------------------------------------------------------------------
__global__ __launch_bounds__(192) void k_head_futr(const float* __restrict__ xfut,
        const float* __restrict__ C1, const float* __restrict__ c0,
        float* __restrict__ out) {
    __shared__ float C1l[192*PP];   // 36.8 KB
    __shared__ float xfl[4*192];    // 3 KB
    int tid = threadIdx.x;
    int r0 = blockIdx.x * 4;
    for (int i = tid; i < 192*PP; i += 192) C1l[i] = C1[i];
    for (int i = tid; i < 4*192; i += 192) xfl[i] = xfut[(size_t)r0*192 + i];
    __syncthreads();
    int p = tid % PP, rr = tid / PP;
    float acc = c0[p];
    #pragma unroll 8
    for (int j = 0; j < 192; ++j) acc += xfl[rr*192 + j] * C1l[j*PP + p];
    out[(size_t)(r0 + rr)*PP + p] = acc;
}

// ---------------------------------------------------------------------------
// Head hist GEMM (bf16 MFMA): out[row,p] += X[row,:12288] @ hWT^T
// A-op = X rows straight from global; B-op = hWT (L2-hot). Split-K x8.
// ---------------------------------------------------------------------------
#define KSL 1536
__global__ __launch_bounds__(256) void k_head_mfma(const unsigned short* __restrict__ X,
        const unsigned short* __restrict__ hWT, float* __restrict__ out) {
    int tid = threadIdx.x;
    int lane = tid & 63, w = tid >> 6;
    int col = lane & 15, q = lane >> 4;
    int m0 = blockIdx.x*64 + w*16;
    int k0 = blockIdx.y*KSL;
    const unsigned short* xp = X + (size_t)(m0 + col)*SH + k0 + q*8;
    const unsigned short* wp = hWT + (size_t)col*SH + k0 + q*8;
    f32x4 acc[3];
    #pragma unroll
    for (int nt = 0; nt < 3; ++nt) acc[nt] = (f32x4){0.f,0.f,0.f,0.f};
    #pragma unroll 4
    for (int kk = 0; kk < KSL; kk += 32) {
        bf16x8 a = *(const bf16x8*)(xp + kk);
        #pragma unroll
        for (int nt = 0; nt < 3; ++nt) {
            bf16x8 b = *(const bf16x8*)(wp + (size_t)nt*16*SH + kk);
            acc[nt] = __builtin_amdgcn_mfma_f32_16x16x32_bf16(a, b, acc[nt], 0, 0, 0);
        }
    }
    int orow = m0 + q*4;
    #pragma unroll
    for (int nt = 0; nt < 3; ++nt)
        #pragma unroll
        for (int r = 0; r < 4; ++r)
            atomicAdd(&out[(size_t)(orow + r)*PP + nt*16 + col], acc[nt][r]);
}

// ---------------------------------------------------------------------------
extern "C" void kernel_launch(void* const* d_in, const int* in_sizes, int n_in,
                              void* d_out, int out_size, void* d_ws, size_t ws_size,
                              hipStream_t stream) {
    const float* x     = (const float*)d_in[0];
    const float* xfut  = (const float*)d_in[1];
    const float* adj   = (const float*)d_in[2];
    const float* emb   = (const float*)d_in[3];
    const float* alpha = (const float*)d_in[4];
    const float* inw   = (const float*)d_in[5];
    const float* inb   = (const float*)d_in[6];
    const float* pW    = (const float*)d_in[7];
    const float* pb    = (const float*)d_in[8];
    const float* tW    = (const float*)d_in[9];
    const float* tb    = (const float*)d_in[10];
    const float* gW    = (const float*)d_in[11];
    const float* gb    = (const float*)d_in[12];
    const float* lnw   = (const float*)d_in[13];
    const float* lnb   = (const float*)d_in[14];
    const float* fW    = (const float*)d_in[15];
    const float* fb    = (const float*)d_in[16];
    const float* hW    = (const float*)d_in[17];
    const float* hb    = (const float*)d_in[18];
    float* out = (float*)d_out;

    // Workspace layout (~160 MB): bufX 157.3MB + adjacency/weights ~1.6MB
    unsigned short* bufX = (unsigned short*)d_ws;
    float* Amat = (float*)(bufX + XSZ);
    float* Araw = Amat + NN*NN;
    float* dvec = Araw + NN*NN;
    unsigned short* tWb = (unsigned short*)(dvec + NN);
    unsigned short* Ab  = tWb + NBLK*SS*SS;
    unsigned short* gWT = Ab + NPAD*KPAD;
    unsigned short* hWT = gWT + NBLK*HH*HH;
    float* C1 = (float*)(hWT + (size_t)PP*SH);
    float* c0 = C1 + 192*PP;

    k_adj_row<<<NN, 64, 0, stream>>>(emb, adj, alpha, Araw, dvec);
    k_adj_scale<<<NN, 256, 0, stream>>>(Araw, dvec, Amat);
    k_prep<<<(NBLK*SS*SS + 255)/256, 256, 0, stream>>>(tW, gW, Amat, tWb, Ab, gWT);
    k_prep2<<<((size_t)PP*SH + 255)/256, 256, 0, stream>>>(hW, fW, fb, hb, hWT, C1, c0);
    k_stage0<<<ROWS, 64, 0, stream>>>(x, inw, inb, pW, pb, emb, bufX);

    for (int i = 0; i < NBLK; ++i) {
        k_temporal_mfma<<<ROWS, 256, 0, stream>>>(bufX, tWb + (size_t)i*SS*SS, tb + i*SS);
        k_spatial_fused<<<dim3(SS, BB), 256, 0, stream>>>(bufX, Ab, gWT + (size_t)i*HH*HH,
                                                          gb + i*HH, lnw + i*HH, lnb + i*HH);
    }
    k_head_futr<<<ROWS/4, 192, 0, stream>>>(xfut, C1, c0, out);
    k_head_mfma<<<dim3(ROWS/64, 8), 256, 0, stream>>>(bufX, hWT, out);
}